// Round 4
// baseline (975.627 us; speedup 1.0000x reference)
//
#include <hip/hip_runtime.h>

#define HIDDEN 2048
#define QUANT  16
#define BATCH  8192
#define HALFD  1024

typedef _Float16 half8  __attribute__((ext_vector_type(8)));
typedef float    floatx16 __attribute__((ext_vector_type(16)));

// exact-GELU via Abramowitz-Stegun 7.1.26 erf (|eps_erf| <= 1.5e-7)
__device__ __forceinline__ float gelu_exact(float v) {
  const float z  = 0.7071067811865476f * v;
  const float az = fabsf(z);
  const float t  = __builtin_amdgcn_rcpf(1.0f + 0.3275911f * az);
  const float p  = t * (0.254829592f +
                   t * (-0.284496736f +
                   t * (1.421413741f +
                   t * (-1.453152027f +
                   t * 1.061405429f))));
  float er = 1.0f - p * __expf(-az * az);
  er = copysignf(er, z);
  return 0.5f * v * (1.0f + er);
}

// ---- x [B][H] f32 -> A tiled fp16: tile(mg=m>>5, kg=k>>4), lane=(m&31)+32*((k>>3)&1), sub=k&7
// flat half index: ((mg*128 + kg)*64 + lane)*8 + sub
__global__ __launch_bounds__(256) void convert_x_tiled(const float* __restrict__ x,
                                                       _Float16* __restrict__ At) {
  __shared__ float ld[64][65];
  const int m0 = blockIdx.x * 64;
  const int k0 = blockIdx.y * 64;
  const int t  = threadIdx.x;
  // read 64 rows x 64 cols, float4-coalesced
  #pragma unroll
  for (int i = 0; i < 4; ++i) {
    const int slot = t + 256 * i;
    const int r = slot >> 4, c = slot & 15;
    const float4 v = *(const float4*)(x + (size_t)(m0 + r) * HIDDEN + k0 + c * 4);
    ld[r][c * 4 + 0] = v.x; ld[r][c * 4 + 1] = v.y;
    ld[r][c * 4 + 2] = v.z; ld[r][c * 4 + 3] = v.w;
  }
  __syncthreads();
  // write 8 tiles (2 mg x 4 kg), 64 lanes each, 16B/lane coalesced
  #pragma unroll
  for (int i = 0; i < 2; ++i) {
    const int slot = t + 256 * i;
    const int tidx = slot >> 6, l = slot & 63;
    const int mgl = tidx >> 2, kgl = tidx & 3;
    const int row = mgl * 32 + (l & 31);
    const int kb  = kgl * 16 + (l >> 5) * 8;
    half8 h;
    #pragma unroll
    for (int j = 0; j < 8; ++j) h[j] = (_Float16)ld[row][kb + j];
    const size_t tile = ((size_t)(m0 / 32 + mgl) * 128 + (k0 / 16 + kgl));
    *(half8*)(At + (tile * 64 + l) * 8) = h;
  }
}

// ---- W1 [Q][H][N] f32 -> B tiled fp16: tile(q, ng=n>>5, kg=h>>4), lane=(n&31)+32*((h>>3)&1), sub=h&7
// flat half index: (((q*32+ng)*128 + kg)*64 + lane)*8 + sub
__global__ __launch_bounds__(256) void transpose_w1_tiled(const float* __restrict__ W1,
                                                          _Float16* __restrict__ Bt) {
  __shared__ float ld[64][33];
  const int q  = blockIdx.z;
  const int h0 = blockIdx.y * 64;
  const int n0 = blockIdx.x * 32;
  const int t  = threadIdx.x;
  const float* src = W1 + (size_t)q * HIDDEN * HALFD;
  // read 64 h-rows x 32 n-cols, float4-coalesced
  #pragma unroll
  for (int i = 0; i < 2; ++i) {
    const int slot = t + 256 * i;
    const int r = slot >> 3, c = slot & 7;
    const float4 v = *(const float4*)(src + (size_t)(h0 + r) * HALFD + n0 + c * 4);
    ld[r][c * 4 + 0] = v.x; ld[r][c * 4 + 1] = v.y;
    ld[r][c * 4 + 2] = v.z; ld[r][c * 4 + 3] = v.w;
  }
  __syncthreads();
  // write 4 tiles (kg), 64 lanes each, gather transposed
  const int kgl = t >> 6, l = t & 63;
  const int nu  = l & 31;
  const int hb  = kgl * 16 + (l >> 5) * 8;
  half8 h;
  #pragma unroll
  for (int j = 0; j < 8; ++j) h[j] = (_Float16)ld[hb + j][nu];
  const size_t tile = (((size_t)q * 32 + n0 / 32) * 128 + (h0 / 16 + kgl));
  *(half8*)(Bt + (tile * 64 + l) * 8) = h;
}

// ---- out[b][q] = b2[q] (atomics accumulate on top) ----
__global__ __launch_bounds__(256) void init_out_kernel(float* __restrict__ out,
                                                       const float* __restrict__ b2) {
  const int i = blockIdx.x * 256 + threadIdx.x;
  out[i] = b2[i & (QUANT - 1)];
}

// ---- fused GEMM + bias + GELU + W2-reduction, NO LDS ----
// Block 128(m) x 128(n), 4 waves 2x2, wave 64x64 via 2x2 frags of 32x32x16 f16.
// Operands pre-tiled in fragment order -> every load is a coalesced 1KB dwordx4.
// Register double-buffer at 32-k granularity; no barriers anywhere.
__global__ __launch_bounds__(256, 3) void qhead_gemm_kernel(
    const _Float16* __restrict__ At,  // tiled A
    const _Float16* __restrict__ Bt,  // tiled B
    const float* __restrict__ b1,     // [QUANT][HALFD]
    const float* __restrict__ W2,     // [QUANT][HALFD]
    float* __restrict__ out) {        // [BATCH][QUANT]
  const int tid  = threadIdx.x;
  const int lane = tid & 63;
  const int wave = tid >> 6;
  const int wm = wave >> 1, wn = wave & 1;
  const int r31 = lane & 31, l5 = lane >> 5;

  const int q     = blockIdx.x >> 3;
  const int nslab = blockIdx.x & 7;
  const int m0    = blockIdx.y << 7;

  const int amg = (m0 >> 5) + wm * 2;                 // A tile-row group (+mf)
  const int bng = q * 32 + nslab * 4 + wn * 2;        // B tile-row group (+nf)

  const half8* pa0 = (const half8*)At + (size_t)(amg + 0) * 8192 + lane;
  const half8* pa1 = (const half8*)At + (size_t)(amg + 1) * 8192 + lane;
  const half8* pb0 = (const half8*)Bt + (size_t)(bng + 0) * 8192 + lane;
  const half8* pb1 = (const half8*)Bt + (size_t)(bng + 1) * 8192 + lane;
  // kgrp stride = 64 half8 (one 32x16 tile = 1KB)

  floatx16 acc[2][2];
  #pragma unroll
  for (int mf = 0; mf < 2; ++mf)
    #pragma unroll
    for (int nf = 0; nf < 2; ++nf)
      #pragma unroll
      for (int i = 0; i < 16; ++i) acc[mf][nf][i] = 0.f;

  // frag buffers [buf][kslice]
  half8 fa0[2][2], fa1[2][2], fb0[2][2], fb1[2][2];

  // preload buf0: kgrps 0,1
  fa0[0][0] = pa0[0];  fa0[0][1] = pa0[64];
  fa1[0][0] = pa1[0];  fa1[0][1] = pa1[64];
  fb0[0][0] = pb0[0];  fb0[0][1] = pb0[64];
  fb1[0][0] = pb1[0];  fb1[0][1] = pb1[64];

  for (int i = 0; i < 32; ++i) {
    const size_t o = (size_t)i * 256;
    // prefetch buf1: kgrps 4i+2, 4i+3
    fa0[1][0] = pa0[o + 128]; fa0[1][1] = pa0[o + 192];
    fa1[1][0] = pa1[o + 128]; fa1[1][1] = pa1[o + 192];
    fb0[1][0] = pb0[o + 128]; fb0[1][1] = pb0[o + 192];
    fb1[1][0] = pb1[o + 128]; fb1[1][1] = pb1[o + 192];
    // MFMA on buf0 (kgrps 4i, 4i+1)
    #pragma unroll
    for (int ks = 0; ks < 2; ++ks) {
      acc[0][0] = __builtin_amdgcn_mfma_f32_32x32x16_f16(fa0[0][ks], fb0[0][ks], acc[0][0], 0, 0, 0);
      acc[0][1] = __builtin_amdgcn_mfma_f32_32x32x16_f16(fa0[0][ks], fb1[0][ks], acc[0][1], 0, 0, 0);
      acc[1][0] = __builtin_amdgcn_mfma_f32_32x32x16_f16(fa1[0][ks], fb0[0][ks], acc[1][0], 0, 0, 0);
      acc[1][1] = __builtin_amdgcn_mfma_f32_32x32x16_f16(fa1[0][ks], fb1[0][ks], acc[1][1], 0, 0, 0);
    }
    // prefetch buf0: kgrps 4i+4, 4i+5
    if (i < 31) {
      fa0[0][0] = pa0[o + 256]; fa0[0][1] = pa0[o + 320];
      fa1[0][0] = pa1[o + 256]; fa1[0][1] = pa1[o + 320];
      fb0[0][0] = pb0[o + 256]; fb0[0][1] = pb0[o + 320];
      fb1[0][0] = pb1[o + 256]; fb1[0][1] = pb1[o + 320];
    }
    // MFMA on buf1 (kgrps 4i+2, 4i+3)
    #pragma unroll
    for (int ks = 0; ks < 2; ++ks) {
      acc[0][0] = __builtin_amdgcn_mfma_f32_32x32x16_f16(fa0[1][ks], fb0[1][ks], acc[0][0], 0, 0, 0);
      acc[0][1] = __builtin_amdgcn_mfma_f32_32x32x16_f16(fa0[1][ks], fb1[1][ks], acc[0][1], 0, 0, 0);
      acc[1][0] = __builtin_amdgcn_mfma_f32_32x32x16_f16(fa1[1][ks], fb0[1][ks], acc[1][0], 0, 0, 0);
      acc[1][1] = __builtin_amdgcn_mfma_f32_32x32x16_f16(fa1[1][ks], fb1[1][ks], acc[1][1], 0, 0, 0);
    }
  }

  // ---- epilogue: bias + exact GELU + *W2, reduce over this wave's 64 columns ----
  // 32x32 C/D layout: col = lane&31, row = (reg&3) + 8*(reg>>2) + 4*(lane>>5)  [m74/m101]
  float rowsum[2][16];
  #pragma unroll
  for (int mf = 0; mf < 2; ++mf)
    #pragma unroll
    for (int r = 0; r < 16; ++r) rowsum[mf][r] = 0.f;

  #pragma unroll
  for (int nf = 0; nf < 2; ++nf) {
    const int ncol = (nslab * 4 + wn * 2 + nf) * 32 + r31;  // col within head
    const float b1v = b1[q * HALFD + ncol];
    const float w2v = W2[q * HALFD + ncol];
    #pragma unroll
    for (int mf = 0; mf < 2; ++mf)
      #pragma unroll
      for (int r = 0; r < 16; ++r)
        rowsum[mf][r] += gelu_exact(acc[mf][nf][r] + b1v) * w2v;
  }
  #pragma unroll
  for (int mf = 0; mf < 2; ++mf) {
    #pragma unroll
    for (int r = 0; r < 16; ++r) {
      float t = rowsum[mf][r];
      t += __shfl_xor(t, 1, 64);
      t += __shfl_xor(t, 2, 64);
      t += __shfl_xor(t, 4, 64);
      t += __shfl_xor(t, 8, 64);
      t += __shfl_xor(t, 16, 64);
      rowsum[mf][r] = t;
    }
  }
  if (r31 == 0) {
    #pragma unroll
    for (int mf = 0; mf < 2; ++mf) {
      const int mbase = m0 + wm * 64 + mf * 32 + 4 * l5;
      #pragma unroll
      for (int r = 0; r < 16; ++r) {
        const int mrow = mbase + (r & 3) + 8 * (r >> 2);
        atomicAdd(&out[(size_t)mrow * QUANT + q], rowsum[mf][r]);
      }
    }
  }
}

extern "C" void kernel_launch(void* const* d_in, const int* in_sizes, int n_in,
                              void* d_out, int out_size, void* d_ws, size_t ws_size,
                              hipStream_t stream) {
  const float* x  = (const float*)d_in[0];
  const float* W1 = (const float*)d_in[1];
  const float* b1 = (const float*)d_in[2];
  const float* W2 = (const float*)d_in[3];
  const float* b2 = (const float*)d_in[4];
  float* out = (float*)d_out;

  _Float16* At = (_Float16*)d_ws;                                    // 32 MB
  _Float16* Bt = (_Float16*)((char*)d_ws +
                 (size_t)BATCH * HIDDEN * sizeof(_Float16));         // 64 MB

  convert_x_tiled<<<dim3(BATCH / 64, HIDDEN / 64), 256, 0, stream>>>(x, At);
  transpose_w1_tiled<<<dim3(HALFD / 32, HIDDEN / 64, QUANT), 256, 0, stream>>>(W1, Bt);
  init_out_kernel<<<BATCH * QUANT / 256, 256, 0, stream>>>(out, b2);
  qhead_gemm_kernel<<<dim3(128, 64), 256, 0, stream>>>(At, Bt, b1, W2, out);
}